// Round 19
// baseline (1313.298 us; speedup 1.0000x reference)
//
#include <hip/hip_runtime.h>

#define B_ 8
#define N_ 8192
#define S_ 1024
#define NS_ 64

typedef float v2f __attribute__((ext_vector_type(2)));
typedef unsigned long long u64;
typedef short bf16x8 __attribute__((ext_vector_type(8)));
typedef float f32x4 __attribute__((ext_vector_type(4)));

// out layout (floats)
#define OUT0 0                 // new_xyz (B,3,1024)
#define OUT1 24576             // new_points (B,128,1024)
#define OUT2 1073152           // new_seed (B,1024); fps int-bits until down_kernel converts

// ws layout (bytes): [0,24576) = bf16 weights; [32768, 32768+2MB) = packed xyzp
#define WS_WBF   0
#define WS_XYZP  32768
#define WS_NEED  (32768 + (size_t)B_ * N_ * 8 * 4)

// ---------------------------------------------------------------------------
// DPP 64-lane reductions (row_shr 1/2/4/8, row_bcast 15/31; result lane 63).
// HW-validated on gfx950 in rounds 6-18.
// ---------------------------------------------------------------------------
template <int CTRL>
static __device__ __forceinline__ float dpp_max_step(float v) {
    int o = __builtin_amdgcn_update_dpp(__float_as_int(v), __float_as_int(v),
                                        CTRL, 0xf, 0xf, false);
    return fmaxf(v, __int_as_float(o));
}
static __device__ __forceinline__ float wave_max_f32(float v) {
    v = dpp_max_step<0x111>(v);
    v = dpp_max_step<0x112>(v);
    v = dpp_max_step<0x114>(v);
    v = dpp_max_step<0x118>(v);
    v = dpp_max_step<0x142>(v);
    v = dpp_max_step<0x143>(v);
    return __int_as_float(__builtin_amdgcn_readlane(__float_as_int(v), 63));
}
template <int CTRL>
static __device__ __forceinline__ unsigned dpp_umin_step(unsigned v) {
    unsigned o = (unsigned)__builtin_amdgcn_update_dpp((int)v, (int)v,
                                                       CTRL, 0xf, 0xf, false);
    return v < o ? v : o;
}
static __device__ __forceinline__ unsigned wave_min_u32(unsigned v) {
    v = dpp_umin_step<0x111>(v);
    v = dpp_umin_step<0x112>(v);
    v = dpp_umin_step<0x114>(v);
    v = dpp_umin_step<0x118>(v);
    v = dpp_umin_step<0x142>(v);
    v = dpp_umin_step<0x143>(v);
    return (unsigned)__builtin_amdgcn_readlane((int)v, 63);
}

// round-to-nearest-even f32 -> bf16 bits
static __device__ __forceinline__ short f2bf(float f) {
    unsigned u = __float_as_uint(f);
    return (short)((u + 0x7FFFu + ((u >> 16) & 1u)) >> 16);
}

// ---------------------------------------------------------------------------
// Kernel 1: farthest point sampling — R7/R9/R11 structure (best measured:
// 1074 us, absmax 0.0). Negative results (do NOT retry): LDS coord slots
// (R8/R10); CONCURRENT producer/consumer fusion (R13/R14 — worker traffic
// inflates the producer's serial path ~2x even at 1 block/CU, t0-only spin).
// ---------------------------------------------------------------------------
#define FPS_T 512
#define FPS_J 8     // float2 per thread (16 points)

__global__ __launch_bounds__(FPS_T, 1) void fps_kernel(const float* __restrict__ xyz,
                                                       float* out) {
    const int b = blockIdx.x;
    const int t = threadIdx.x;          // 0..511
    const int lane = t & 63;
    const float* X = xyz + b * 3 * N_;

    v2f px2[FPS_J], py2[FPS_J], pz2[FPS_J], dist2[FPS_J];
#pragma unroll
    for (int j = 0; j < FPS_J; ++j) {
        int n = t + 1024 * j;
        px2[j] = (v2f){X[n], X[n + 512]};
        py2[j] = (v2f){X[N_ + n], X[N_ + n + 512]};
        pz2[j] = (v2f){X[2 * N_ + n], X[2 * N_ + n + 512]};
        dist2[j] = (v2f){1e10f, 1e10f};
    }

    __shared__ u64 pairs[2];
    if (t == 0) { pairs[0] = 0ull; pairs[1] = 0ull; }
    __syncthreads();

    float* oseed = out + OUT2 + b * S_;

    int ci = 0;
    float c0 = X[0], c1 = X[N_], c2 = X[2 * N_];

    for (int step = 0; step < S_; ++step) {
        if (t == 0) oseed[step] = __int_as_float(ci);

        v2f mv = (v2f){-1.0f, -1.0f};
        {
#pragma clang fp contract(off)
            v2f c0v = (v2f){c0, c0};
            v2f c1v = (v2f){c1, c1};
            v2f c2v = (v2f){c2, c2};
#pragma unroll
            for (int j = 0; j < FPS_J; ++j) {
                v2f e0 = px2[j] - c0v;
                v2f e1 = py2[j] - c1v;
                v2f e2 = pz2[j] - c2v;
                v2f q0 = e0 * e0;
                v2f q1 = e1 * e1;
                v2f q2 = e2 * e2;
                v2f d  = (q0 + q1) + q2;
                v2f dm = __builtin_elementwise_min(dist2[j], d);
                dist2[j] = dm;
                mv = __builtin_elementwise_max(mv, dm);
            }
        }
        float m = fmaxf(mv.x, mv.y);
        float wmax = wave_max_f32(m);

        unsigned mask = 0u;
#pragma unroll
        for (int j = 0; j < FPS_J; ++j) {
            if (dist2[j].x == wmax) mask |= (1u << (2 * j));
            if (dist2[j].y == wmax) mask |= (1u << (2 * j + 1));
        }
        unsigned cand = 0xffffffffu;
        if (mask) {
            int bit = __ffs(mask) - 1;
            cand = (unsigned)(t + (bit << 9));
        }
        unsigned widx = wave_min_u32(cand);

        if (lane == 0) {
            u64 pv = ((u64)(step + 1) << 45) |
                     ((u64)__float_as_uint(wmax) << 13) |
                     (u64)(8191u - widx);
            atomicMax(&pairs[(step + 1) & 1], pv);
        }
        __syncthreads();

        u64 p = pairs[(step + 1) & 1];
        ci = 8191 - (int)(p & 0x1fffull);
        int cu = __builtin_amdgcn_readfirstlane(ci);
        c0 = X[cu];
        c1 = X[N_ + cu];
        c2 = X[2 * N_ + cu];
    }
}

// ---------------------------------------------------------------------------
// Kernel 1b: one-shot weight conversion w1 (64x64) + w2 (128x64) -> bf16.
// ---------------------------------------------------------------------------
__global__ __launch_bounds__(256) void wconv_kernel(const float* __restrict__ w1,
                                                    const float* __restrict__ w2,
                                                    short* __restrict__ wbf) {
    int t = blockIdx.x * 256 + threadIdx.x;   // 0..12287
    float v = (t < 4096) ? w1[t] : w2[t - 4096];
    wbf[t] = f2bf(v);
}

// ---------------------------------------------------------------------------
// Kernel 1c: pack xyz+pts SoA -> interleaved 8-float AoS:
//   xyzp[(b*N+n)*8 + {0..5}] = {x, y, z, px, py, pz}  (6,7 unused)
// Ball query then needs 1 dwordx4/point-chunk instead of 3 dwords; f0 gather
// 2 dwordx4 instead of 6 scattered dwords.
// ---------------------------------------------------------------------------
__global__ __launch_bounds__(256) void pack_kernel(const float* __restrict__ xyz,
                                                   const float* __restrict__ pts,
                                                   float* __restrict__ xyzp) {
    int t = blockIdx.x * 256 + threadIdx.x;   // 0..65535
    int b = t >> 13, n = t & 8191;
    const float* X = xyz + b * 3 * N_;
    const float* P = pts + b * 3 * N_;
    float4 lo = make_float4(X[n], X[N_ + n], X[2 * N_ + n], P[n]);
    float4 hi = make_float4(P[N_ + n], P[2 * N_ + n], 0.f, 0.f);
    *(float4*)&xyzp[(size_t)t * 8] = lo;
    *(float4*)&xyzp[(size_t)t * 8 + 4] = hi;
}

// ---------------------------------------------------------------------------
// Kernel 2: fused downstream — one block (256 thr, 4 waves) per centroid:
//   (a) read fps idx bits from OUT2 (broadcast), write new_xyz + new_seed
//   (b) 4-wave ball query over packed xyzp (1 dwordx4/chunk), fixed 16 iters
//   (c) MFMA mlp (R16-verified layouts), pre-converted bf16 weights.
// Falls back to SoA loads when xyzp == nullptr (small-ws harness).
// ---------------------------------------------------------------------------
__global__ __launch_bounds__(256) void down_kernel(
    const float* __restrict__ xyz, const float* __restrict__ pts,
    const int* __restrict__ seed,
    const float* __restrict__ w0, const float* __restrict__ b0,
    const float* __restrict__ g0, const float* __restrict__ be0,
    const float* __restrict__ m0, const float* __restrict__ v0,
    const float* __restrict__ w1, const float* __restrict__ b1,
    const float* __restrict__ g1, const float* __restrict__ be1,
    const float* __restrict__ m1, const float* __restrict__ v1,
    const float* __restrict__ w2, const float* __restrict__ b2,
    const float* __restrict__ g2, const float* __restrict__ be2,
    const float* __restrict__ m2, const float* __restrict__ v2,
    float* out, const short* __restrict__ wbf,
    const float* __restrict__ xyzp) {
    const int sg = blockIdx.x;
    const int b = sg >> 10, s = sg & 1023;
    const int t = threadIdx.x;
    const int lane = t & 63;
    const int wq = __builtin_amdgcn_readfirstlane(t >> 6);   // 0..3
    const int ln = lane & 15;
    const int quad = (lane >> 4) & 3;

    __shared__ float f0[64 * 9];
    __shared__ short featA[64 * 72];
    __shared__ short featB[64 * 72];
    __shared__ float wmaxs[4 * 132];
    __shared__ float scs[256], ofs[256];
    __shared__ int cand[4 * 64];
    __shared__ int cnts[4];
    __shared__ int gis[64];

    const float* X = xyz + b * 3 * N_;
    const float* XP = (xyzp != nullptr) ? (xyzp + (size_t)b * N_ * 8) : nullptr;

    // (a) broadcast read of fps index; centroid coords
    int ci = __float_as_int(out[OUT2 + sg]) & 8191;
    float cx = X[ci], cy = X[N_ + ci], cz = X[2 * N_ + ci];

    // per-channel BN fold (one sqrt+div per thread)
    {
        float sc, of;
        if (t < 64) {
            int c = t;
            sc = g0[c] / sqrtf(v0[c] + 1e-5f);
            of = (b0[c] - m0[c]) * sc + be0[c];
        } else if (t < 128) {
            int c = t - 64;
            sc = g1[c] / sqrtf(v1[c] + 1e-5f);
            of = (b1[c] - m1[c]) * sc + be1[c];
        } else {
            int c = t - 128;
            sc = g2[c] / sqrtf(v2[c] + 1e-5f);
            of = (b2[c] - m2[c]) * sc + be2[c];
        }
        scs[t] = sc;
        ofs[t] = of;
    }
    __syncthreads();   // all OUT2 reads complete (vmcnt drained) before overwrite

    if (t == 0) {
        out[OUT0 + (b * 3 + 0) * S_ + s] = cx;
        out[OUT0 + (b * 3 + 1) * S_ + s] = cy;
        out[OUT0 + (b * 3 + 2) * S_ + s] = cz;
        out[OUT2 + sg] = (float)seed[b * N_ + ci];
    }

    // (b) 4-wave ball query: wave wq scans [2048*wq, 2048*wq+2048), 16 iters
    {
        int cnt = 0;
        const int wbase = wq << 11;
        if (XP != nullptr) {
#pragma unroll 2
            for (int base = 0; base < 2048; base += 128) {
                int n0 = wbase + base + lane;
                int n1 = n0 + 64;
                float4 p0 = *(const float4*)&XP[(size_t)n0 * 8];
                float4 p1 = *(const float4*)&XP[(size_t)n1 * 8];
                float e0 = p0.x - cx, e1 = p0.y - cy, e2 = p0.z - cz;
                float d0 = fmaf(e2, e2, fmaf(e1, e1, e0 * e0));
                float q0 = p1.x - cx, q1 = p1.y - cy, q2 = p1.z - cz;
                float d1 = fmaf(q2, q2, fmaf(q1, q1, q0 * q0));

                u64 mask0 = __ballot(d0 <= 0.04f);
                if (mask0) {
                    int pos = cnt + (int)__popcll(mask0 & ((1ull << lane) - 1ull));
                    if ((d0 <= 0.04f) && pos < NS_) cand[(wq << 6) + pos] = n0;
                    cnt += (int)__popcll(mask0);
                }
                u64 mask1 = __ballot(d1 <= 0.04f);
                if (mask1) {
                    int pos = cnt + (int)__popcll(mask1 & ((1ull << lane) - 1ull));
                    if ((d1 <= 0.04f) && pos < NS_) cand[(wq << 6) + pos] = n1;
                    cnt += (int)__popcll(mask1);
                }
            }
        } else {
#pragma unroll 2
            for (int base = 0; base < 2048; base += 128) {
                int n0 = wbase + base + lane;
                int n1 = n0 + 64;
                float x0 = X[n0], y0 = X[N_ + n0], z0 = X[2 * N_ + n0];
                float x1 = X[n1], y1 = X[N_ + n1], z1 = X[2 * N_ + n1];
                float e0 = x0 - cx, e1 = y0 - cy, e2 = z0 - cz;
                float d0 = fmaf(e2, e2, fmaf(e1, e1, e0 * e0));
                float q0 = x1 - cx, q1 = y1 - cy, q2 = z1 - cz;
                float d1 = fmaf(q2, q2, fmaf(q1, q1, q0 * q0));

                u64 mask0 = __ballot(d0 <= 0.04f);
                if (mask0) {
                    int pos = cnt + (int)__popcll(mask0 & ((1ull << lane) - 1ull));
                    if ((d0 <= 0.04f) && pos < NS_) cand[(wq << 6) + pos] = n0;
                    cnt += (int)__popcll(mask0);
                }
                u64 mask1 = __ballot(d1 <= 0.04f);
                if (mask1) {
                    int pos = cnt + (int)__popcll(mask1 & ((1ull << lane) - 1ull));
                    if ((d1 <= 0.04f) && pos < NS_) cand[(wq << 6) + pos] = n1;
                    cnt += (int)__popcll(mask1);
                }
            }
        }
        if (lane == 0) cnts[wq] = cnt;
    }
    __syncthreads();

    // merge: first 64 in global ascending index order; pad with overall-first
    if (t < 64) {
        int k = t;
        int start = 0, sel = -1, firstv = -1;
#pragma unroll
        for (int w = 0; w < 4; ++w) {
            int cw = min(cnts[w], NS_);
            if (firstv < 0 && cw > 0) firstv = cand[(w << 6)];
            if (sel < 0 && k < start + cw) sel = cand[(w << 6) + (k - start)];
            start += cw;
        }
        if (sel < 0) sel = firstv;
        gis[t] = sel;
    }
    __syncthreads();

    if (t < 64) {
        int gidx = gis[t] & 8191;
        if (XP != nullptr) {
            float4 lo = *(const float4*)&XP[(size_t)gidx * 8];
            float4 hi = *(const float4*)&XP[(size_t)gidx * 8 + 4];
            f0[t * 9 + 0] = lo.x - cx;
            f0[t * 9 + 1] = lo.y - cy;
            f0[t * 9 + 2] = lo.z - cz;
            f0[t * 9 + 3] = lo.w;
            f0[t * 9 + 4] = hi.x;
            f0[t * 9 + 5] = hi.y;
        } else {
            const float* P = pts + b * 3 * N_;
            f0[t * 9 + 0] = X[gidx] - cx;
            f0[t * 9 + 1] = X[N_ + gidx] - cy;
            f0[t * 9 + 2] = X[2 * N_ + gidx] - cz;
            f0[t * 9 + 3] = P[gidx];
            f0[t * 9 + 4] = P[N_ + gidx];
            f0[t * 9 + 5] = P[2 * N_ + gidx];
        }
    }
    __syncthreads();

    // (c) layer 0: 6 -> 64 on VALU; point = lane, wave owns 16-channel slice
    {
        float in[6];
#pragma unroll
        for (int c = 0; c < 6; ++c) in[c] = f0[lane * 9 + c];
#pragma unroll 1
        for (int i = 0; i < 16; i += 4) {
            int o = wq * 16 + i;
            float a0 = 0.f, a1 = 0.f, a2 = 0.f, a3 = 0.f;
#pragma unroll
            for (int c = 0; c < 6; ++c) {
                float rc = in[c];
                a0 = fmaf(rc, w0[(o + 0) * 6 + c], a0);
                a1 = fmaf(rc, w0[(o + 1) * 6 + c], a1);
                a2 = fmaf(rc, w0[(o + 2) * 6 + c], a2);
                a3 = fmaf(rc, w0[(o + 3) * 6 + c], a3);
            }
            featA[lane * 72 + o + 0] = f2bf(fmaxf(fmaf(a0, scs[o + 0], ofs[o + 0]), 0.f));
            featA[lane * 72 + o + 1] = f2bf(fmaxf(fmaf(a1, scs[o + 1], ofs[o + 1]), 0.f));
            featA[lane * 72 + o + 2] = f2bf(fmaxf(fmaf(a2, scs[o + 2], ofs[o + 2]), 0.f));
            featA[lane * 72 + o + 3] = f2bf(fmaxf(fmaf(a3, scs[o + 3], ofs[o + 3]), 0.f));
        }
    }
    __syncthreads();

    const int arow = 16 * wq + ln;   // this wave's m-tile row for A-frags
    const bool usebf = (wbf != nullptr);

    // layer 1: 64 -> 64 via MFMA (4 ntiles x 2 ksteps)
    {
        bf16x8 a1f[2];
#pragma unroll
        for (int ks = 0; ks < 2; ++ks)
            a1f[ks] = *(const bf16x8*)&featA[arow * 72 + ks * 32 + quad * 8];

#pragma unroll
        for (int nt = 0; nt < 4; ++nt) {
            f32x4 acc = {0.f, 0.f, 0.f, 0.f};
#pragma unroll
            for (int ks = 0; ks < 2; ++ks) {
                int off = (nt * 16 + ln) * 64 + ks * 32 + quad * 8;
                bf16x8 bf;
                if (usebf) {
                    bf = *(const bf16x8*)&wbf[off];
                } else {
                    const float* wr = w1 + off;
                    float4 p = *(const float4*)wr;
                    float4 q = *(const float4*)(wr + 4);
                    bf = (bf16x8){f2bf(p.x), f2bf(p.y), f2bf(p.z), f2bf(p.w),
                                  f2bf(q.x), f2bf(q.y), f2bf(q.z), f2bf(q.w)};
                }
                acc = __builtin_amdgcn_mfma_f32_16x16x32_bf16(a1f[ks], bf, acc, 0, 0, 0);
            }
            int o = nt * 16 + ln;
            float sc = scs[64 + o], of = ofs[64 + o];
#pragma unroll
            for (int reg = 0; reg < 4; ++reg) {
                float y = fmaxf(fmaf(acc[reg], sc, of), 0.f);
                featB[(16 * wq + quad * 4 + reg) * 72 + o] = f2bf(y);
            }
        }
    }
    // no barrier: each wave reads back only its own m-tile rows

    // layer 2: 64 -> 128 via MFMA (8 ntiles x 2 ksteps) + fused k-max
    {
        bf16x8 a2f[2];
#pragma unroll
        for (int ks = 0; ks < 2; ++ks)
            a2f[ks] = *(const bf16x8*)&featB[arow * 72 + ks * 32 + quad * 8];

#pragma unroll
        for (int nt = 0; nt < 8; ++nt) {
            f32x4 acc = {0.f, 0.f, 0.f, 0.f};
#pragma unroll
            for (int ks = 0; ks < 2; ++ks) {
                int off = (nt * 16 + ln) * 64 + ks * 32 + quad * 8;
                bf16x8 bf;
                if (usebf) {
                    bf = *(const bf16x8*)&wbf[4096 + off];
                } else {
                    const float* wr = w2 + off;
                    float4 p = *(const float4*)wr;
                    float4 q = *(const float4*)(wr + 4);
                    bf = (bf16x8){f2bf(p.x), f2bf(p.y), f2bf(p.z), f2bf(p.w),
                                  f2bf(q.x), f2bf(q.y), f2bf(q.z), f2bf(q.w)};
                }
                acc = __builtin_amdgcn_mfma_f32_16x16x32_bf16(a2f[ks], bf, acc, 0, 0, 0);
            }
            int o = nt * 16 + ln;
            float sc = scs[128 + o], of = ofs[128 + o];
            float m = -1.f;
#pragma unroll
            for (int reg = 0; reg < 4; ++reg) {
                float y = fmaxf(fmaf(acc[reg], sc, of), 0.f);
                m = fmaxf(m, y);
            }
            m = fmaxf(m, __shfl_xor(m, 16, 64));
            m = fmaxf(m, __shfl_xor(m, 32, 64));
            if (lane < 16) wmaxs[wq * 132 + o] = m;
        }
    }
    __syncthreads();

    // final: max over the 4 waves' m-tiles, store new_points
    if (t < 128) {
        float m = fmaxf(fmaxf(wmaxs[0 * 132 + t], wmaxs[1 * 132 + t]),
                        fmaxf(wmaxs[2 * 132 + t], wmaxs[3 * 132 + t]));
        out[OUT1 + (b * 128 + t) * S_ + s] = m;
    }
}

extern "C" void kernel_launch(void* const* d_in, const int* in_sizes, int n_in,
                              void* d_out, int out_size, void* d_ws, size_t ws_size,
                              hipStream_t stream) {
    const float* xyz  = (const float*)d_in[0];
    const float* pts  = (const float*)d_in[1];
    const int*   seed = (const int*)d_in[2];
    const float* w0 = (const float*)d_in[3];
    const float* b0 = (const float*)d_in[4];
    const float* g0 = (const float*)d_in[5];
    const float* be0 = (const float*)d_in[6];
    const float* m0 = (const float*)d_in[7];
    const float* v0 = (const float*)d_in[8];
    const float* w1 = (const float*)d_in[9];
    const float* b1 = (const float*)d_in[10];
    const float* g1 = (const float*)d_in[11];
    const float* be1 = (const float*)d_in[12];
    const float* m1 = (const float*)d_in[13];
    const float* v1 = (const float*)d_in[14];
    const float* w2 = (const float*)d_in[15];
    const float* b2 = (const float*)d_in[16];
    const float* g2 = (const float*)d_in[17];
    const float* be2 = (const float*)d_in[18];
    const float* m2 = (const float*)d_in[19];
    const float* v2 = (const float*)d_in[20];
    float* out = (float*)d_out;

    short* wbf = nullptr;
    float* xyzp = nullptr;
    if (ws_size >= 12288 * sizeof(short)) {
        wbf = (short*)((char*)d_ws + WS_WBF);
        wconv_kernel<<<dim3(48), dim3(256), 0, stream>>>(w1, w2, wbf);
    }
    if (ws_size >= WS_NEED) {
        xyzp = (float*)((char*)d_ws + WS_XYZP);
        pack_kernel<<<dim3(B_ * N_ / 256), dim3(256), 0, stream>>>(xyz, pts, xyzp);
    }

    fps_kernel<<<dim3(B_), dim3(FPS_T), 0, stream>>>(xyz, out);
    down_kernel<<<dim3(B_ * S_), dim3(256), 0, stream>>>(xyz, pts, seed,
        w0, b0, g0, be0, m0, v0,
        w1, b1, g1, be1, m1, v1,
        w2, b2, g2, be2, m2, v2,
        out, wbf, xyzp);
}

// Round 20
// 1296.159 us; speedup vs baseline: 1.0132x; 1.0132x over previous
//
#include <hip/hip_runtime.h>

#define B_ 8
#define N_ 8192
#define S_ 1024
#define NS_ 64

typedef float v2f __attribute__((ext_vector_type(2)));
typedef unsigned long long u64;
typedef short bf16x8 __attribute__((ext_vector_type(8)));
typedef float f32x4 __attribute__((ext_vector_type(4)));

// out layout (floats)
#define OUT0 0                 // new_xyz (B,3,1024)
#define OUT1 24576             // new_points (B,128,1024)
#define OUT2 1073152           // new_seed (B,1024); fps int-bits until down_kernel converts

// ---------------------------------------------------------------------------
// DPP 64-lane reductions (row_shr 1/2/4/8, row_bcast 15/31; result lane 63).
// HW-validated on gfx950 in rounds 6-19.
// ---------------------------------------------------------------------------
template <int CTRL>
static __device__ __forceinline__ float dpp_max_step(float v) {
    int o = __builtin_amdgcn_update_dpp(__float_as_int(v), __float_as_int(v),
                                        CTRL, 0xf, 0xf, false);
    return fmaxf(v, __int_as_float(o));
}
static __device__ __forceinline__ float wave_max_f32(float v) {
    v = dpp_max_step<0x111>(v);
    v = dpp_max_step<0x112>(v);
    v = dpp_max_step<0x114>(v);
    v = dpp_max_step<0x118>(v);
    v = dpp_max_step<0x142>(v);
    v = dpp_max_step<0x143>(v);
    return __int_as_float(__builtin_amdgcn_readlane(__float_as_int(v), 63));
}
template <int CTRL>
static __device__ __forceinline__ unsigned dpp_umin_step(unsigned v) {
    unsigned o = (unsigned)__builtin_amdgcn_update_dpp((int)v, (int)v,
                                                       CTRL, 0xf, 0xf, false);
    return v < o ? v : o;
}
static __device__ __forceinline__ unsigned wave_min_u32(unsigned v) {
    v = dpp_umin_step<0x111>(v);
    v = dpp_umin_step<0x112>(v);
    v = dpp_umin_step<0x114>(v);
    v = dpp_umin_step<0x118>(v);
    v = dpp_umin_step<0x142>(v);
    v = dpp_umin_step<0x143>(v);
    return (unsigned)__builtin_amdgcn_readlane((int)v, 63);
}

// round-to-nearest-even f32 -> bf16 bits
static __device__ __forceinline__ short f2bf(float f) {
    unsigned u = __float_as_uint(f);
    return (short)((u + 0x7FFFu + ((u >> 16) & 1u)) >> 16);
}

// ---------------------------------------------------------------------------
// Kernel 1: farthest point sampling — R7/R9/R11 structure (best measured:
// 1074 us, absmax 0.0). Negative results (do NOT retry): LDS coord slots
// (R8/R10); CONCURRENT producer/consumer fusion (R13/R14 — worker traffic
// inflates the producer's serial path ~2x even at 1 block/CU, t0-only spin).
// ---------------------------------------------------------------------------
#define FPS_T 512
#define FPS_J 8     // float2 per thread (16 points)

__global__ __launch_bounds__(FPS_T, 1) void fps_kernel(const float* __restrict__ xyz,
                                                       float* out) {
    const int b = blockIdx.x;
    const int t = threadIdx.x;          // 0..511
    const int lane = t & 63;
    const float* X = xyz + b * 3 * N_;

    v2f px2[FPS_J], py2[FPS_J], pz2[FPS_J], dist2[FPS_J];
#pragma unroll
    for (int j = 0; j < FPS_J; ++j) {
        int n = t + 1024 * j;
        px2[j] = (v2f){X[n], X[n + 512]};
        py2[j] = (v2f){X[N_ + n], X[N_ + n + 512]};
        pz2[j] = (v2f){X[2 * N_ + n], X[2 * N_ + n + 512]};
        dist2[j] = (v2f){1e10f, 1e10f};
    }

    __shared__ u64 pairs[2];
    if (t == 0) { pairs[0] = 0ull; pairs[1] = 0ull; }
    __syncthreads();

    float* oseed = out + OUT2 + b * S_;

    int ci = 0;
    float c0 = X[0], c1 = X[N_], c2 = X[2 * N_];

    for (int step = 0; step < S_; ++step) {
        if (t == 0) oseed[step] = __int_as_float(ci);

        v2f mv = (v2f){-1.0f, -1.0f};
        {
#pragma clang fp contract(off)
            v2f c0v = (v2f){c0, c0};
            v2f c1v = (v2f){c1, c1};
            v2f c2v = (v2f){c2, c2};
#pragma unroll
            for (int j = 0; j < FPS_J; ++j) {
                v2f e0 = px2[j] - c0v;
                v2f e1 = py2[j] - c1v;
                v2f e2 = pz2[j] - c2v;
                v2f q0 = e0 * e0;
                v2f q1 = e1 * e1;
                v2f q2 = e2 * e2;
                v2f d  = (q0 + q1) + q2;
                v2f dm = __builtin_elementwise_min(dist2[j], d);
                dist2[j] = dm;
                mv = __builtin_elementwise_max(mv, dm);
            }
        }
        float m = fmaxf(mv.x, mv.y);
        float wmax = wave_max_f32(m);

        unsigned mask = 0u;
#pragma unroll
        for (int j = 0; j < FPS_J; ++j) {
            if (dist2[j].x == wmax) mask |= (1u << (2 * j));
            if (dist2[j].y == wmax) mask |= (1u << (2 * j + 1));
        }
        unsigned cand = 0xffffffffu;
        if (mask) {
            int bit = __ffs(mask) - 1;
            cand = (unsigned)(t + (bit << 9));
        }
        unsigned widx = wave_min_u32(cand);

        if (lane == 0) {
            u64 pv = ((u64)(step + 1) << 45) |
                     ((u64)__float_as_uint(wmax) << 13) |
                     (u64)(8191u - widx);
            atomicMax(&pairs[(step + 1) & 1], pv);
        }
        __syncthreads();

        u64 p = pairs[(step + 1) & 1];
        ci = 8191 - (int)(p & 0x1fffull);
        int cu = __builtin_amdgcn_readfirstlane(ci);
        c0 = X[cu];
        c1 = X[N_ + cu];
        c2 = X[2 * N_ + cu];
    }
}

// ---------------------------------------------------------------------------
// Kernel 1b: one-shot weight conversion w1 (64x64) + w2 (128x64) -> bf16 in
// d_ws. Shared by all 8192 down_kernel blocks.
// ---------------------------------------------------------------------------
__global__ __launch_bounds__(256) void wconv_kernel(const float* __restrict__ w1,
                                                    const float* __restrict__ w2,
                                                    short* __restrict__ wbf) {
    int t = blockIdx.x * 256 + threadIdx.x;   // 0..12287
    float v = (t < 4096) ? w1[t] : w2[t - 4096];
    wbf[t] = f2bf(v);
}

// ---------------------------------------------------------------------------
// Kernel 2: fused downstream — one block (256 thr, 4 waves) per centroid:
//   (a) read fps idx bits from OUT2 (broadcast), write new_xyz + new_seed
//   (b) 4-wave ball query, FIXED 16-iteration loop over SoA xyz (R19
//       negative result: interleaved AoS packing doubles fetched bytes —
//       32 B stride wastes half of each cacheline; SoA is layout-optimal)
//   (c) MFMA mlp (R16-verified layouts); pre-converted bf16 weights.
// ---------------------------------------------------------------------------
__global__ __launch_bounds__(256) void down_kernel(
    const float* __restrict__ xyz, const float* __restrict__ pts,
    const int* __restrict__ seed,
    const float* __restrict__ w0, const float* __restrict__ b0,
    const float* __restrict__ g0, const float* __restrict__ be0,
    const float* __restrict__ m0, const float* __restrict__ v0,
    const float* __restrict__ w1, const float* __restrict__ b1,
    const float* __restrict__ g1, const float* __restrict__ be1,
    const float* __restrict__ m1, const float* __restrict__ v1,
    const float* __restrict__ w2, const float* __restrict__ b2,
    const float* __restrict__ g2, const float* __restrict__ be2,
    const float* __restrict__ m2, const float* __restrict__ v2,
    float* out, const short* __restrict__ wbf) {
    const int sg = blockIdx.x;
    const int b = sg >> 10, s = sg & 1023;
    const int t = threadIdx.x;
    const int lane = t & 63;
    const int wq = __builtin_amdgcn_readfirstlane(t >> 6);   // 0..3
    const int ln = lane & 15;
    const int quad = (lane >> 4) & 3;

    __shared__ float f0[64 * 9];
    __shared__ short featA[64 * 72];
    __shared__ short featB[64 * 72];
    __shared__ float wmaxs[4 * 132];
    __shared__ float scs[256], ofs[256];
    __shared__ int cand[4 * 64];
    __shared__ int cnts[4];
    __shared__ int gis[64];

    const float* X = xyz + b * 3 * N_;

    // (a) broadcast read of fps index; centroid coords
    int ci = __float_as_int(out[OUT2 + sg]) & 8191;
    float cx = X[ci], cy = X[N_ + ci], cz = X[2 * N_ + ci];

    // per-channel BN fold (one sqrt+div per thread)
    {
        float sc, of;
        if (t < 64) {
            int c = t;
            sc = g0[c] / sqrtf(v0[c] + 1e-5f);
            of = (b0[c] - m0[c]) * sc + be0[c];
        } else if (t < 128) {
            int c = t - 64;
            sc = g1[c] / sqrtf(v1[c] + 1e-5f);
            of = (b1[c] - m1[c]) * sc + be1[c];
        } else {
            int c = t - 128;
            sc = g2[c] / sqrtf(v2[c] + 1e-5f);
            of = (b2[c] - m2[c]) * sc + be2[c];
        }
        scs[t] = sc;
        ofs[t] = of;
    }
    __syncthreads();   // all OUT2 reads complete (vmcnt drained) before overwrite

    if (t == 0) {
        out[OUT0 + (b * 3 + 0) * S_ + s] = cx;
        out[OUT0 + (b * 3 + 1) * S_ + s] = cy;
        out[OUT0 + (b * 3 + 2) * S_ + s] = cz;
        out[OUT2 + sg] = (float)seed[b * N_ + ci];
    }

    // (b) 4-wave ball query: wave wq scans [2048*wq, 2048*wq+2048), 16 iters
    {
        int cnt = 0;
        const int wbase = wq << 11;
#pragma unroll 2
        for (int base = 0; base < 2048; base += 128) {
            int n0 = wbase + base + lane;
            int n1 = n0 + 64;
            float x0 = X[n0], y0 = X[N_ + n0], z0 = X[2 * N_ + n0];
            float x1 = X[n1], y1 = X[N_ + n1], z1 = X[2 * N_ + n1];
            float e0 = x0 - cx, e1 = y0 - cy, e2 = z0 - cz;
            float d0 = fmaf(e2, e2, fmaf(e1, e1, e0 * e0));
            float q0 = x1 - cx, q1 = y1 - cy, q2 = z1 - cz;
            float d1 = fmaf(q2, q2, fmaf(q1, q1, q0 * q0));

            u64 mask0 = __ballot(d0 <= 0.04f);
            if (mask0) {
                int pos = cnt + (int)__popcll(mask0 & ((1ull << lane) - 1ull));
                if ((d0 <= 0.04f) && pos < NS_) cand[(wq << 6) + pos] = n0;
                cnt += (int)__popcll(mask0);
            }
            u64 mask1 = __ballot(d1 <= 0.04f);
            if (mask1) {
                int pos = cnt + (int)__popcll(mask1 & ((1ull << lane) - 1ull));
                if ((d1 <= 0.04f) && pos < NS_) cand[(wq << 6) + pos] = n1;
                cnt += (int)__popcll(mask1);
            }
        }
        if (lane == 0) cnts[wq] = cnt;
    }
    __syncthreads();

    // merge: first 64 in global ascending index order; pad with overall-first
    if (t < 64) {
        int k = t;
        int start = 0, sel = -1, firstv = -1;
#pragma unroll
        for (int w = 0; w < 4; ++w) {
            int cw = min(cnts[w], NS_);
            if (firstv < 0 && cw > 0) firstv = cand[(w << 6)];
            if (sel < 0 && k < start + cw) sel = cand[(w << 6) + (k - start)];
            start += cw;
        }
        if (sel < 0) sel = firstv;
        gis[t] = sel;
    }
    __syncthreads();

    if (t < 64) {
        int gidx = gis[t] & 8191;
        const float* P = pts + b * 3 * N_;
        f0[t * 9 + 0] = X[gidx] - cx;
        f0[t * 9 + 1] = X[N_ + gidx] - cy;
        f0[t * 9 + 2] = X[2 * N_ + gidx] - cz;
        f0[t * 9 + 3] = P[gidx];
        f0[t * 9 + 4] = P[N_ + gidx];
        f0[t * 9 + 5] = P[2 * N_ + gidx];
    }
    __syncthreads();

    // (c) layer 0: 6 -> 64 on VALU; point = lane, wave owns 16-channel slice
    {
        float in[6];
#pragma unroll
        for (int c = 0; c < 6; ++c) in[c] = f0[lane * 9 + c];
#pragma unroll 1
        for (int i = 0; i < 16; i += 4) {
            int o = wq * 16 + i;
            float a0 = 0.f, a1 = 0.f, a2 = 0.f, a3 = 0.f;
#pragma unroll
            for (int c = 0; c < 6; ++c) {
                float rc = in[c];
                a0 = fmaf(rc, w0[(o + 0) * 6 + c], a0);
                a1 = fmaf(rc, w0[(o + 1) * 6 + c], a1);
                a2 = fmaf(rc, w0[(o + 2) * 6 + c], a2);
                a3 = fmaf(rc, w0[(o + 3) * 6 + c], a3);
            }
            featA[lane * 72 + o + 0] = f2bf(fmaxf(fmaf(a0, scs[o + 0], ofs[o + 0]), 0.f));
            featA[lane * 72 + o + 1] = f2bf(fmaxf(fmaf(a1, scs[o + 1], ofs[o + 1]), 0.f));
            featA[lane * 72 + o + 2] = f2bf(fmaxf(fmaf(a2, scs[o + 2], ofs[o + 2]), 0.f));
            featA[lane * 72 + o + 3] = f2bf(fmaxf(fmaf(a3, scs[o + 3], ofs[o + 3]), 0.f));
        }
    }
    __syncthreads();

    const int arow = 16 * wq + ln;   // this wave's m-tile row for A-frags
    const bool usebf = (wbf != nullptr);

    // layer 1: 64 -> 64 via MFMA (4 ntiles x 2 ksteps)
    {
        bf16x8 a1f[2];
#pragma unroll
        for (int ks = 0; ks < 2; ++ks)
            a1f[ks] = *(const bf16x8*)&featA[arow * 72 + ks * 32 + quad * 8];

#pragma unroll
        for (int nt = 0; nt < 4; ++nt) {
            f32x4 acc = {0.f, 0.f, 0.f, 0.f};
#pragma unroll
            for (int ks = 0; ks < 2; ++ks) {
                int off = (nt * 16 + ln) * 64 + ks * 32 + quad * 8;
                bf16x8 bf;
                if (usebf) {
                    bf = *(const bf16x8*)&wbf[off];
                } else {
                    const float* wr = w1 + off;
                    float4 p = *(const float4*)wr;
                    float4 q = *(const float4*)(wr + 4);
                    bf = (bf16x8){f2bf(p.x), f2bf(p.y), f2bf(p.z), f2bf(p.w),
                                  f2bf(q.x), f2bf(q.y), f2bf(q.z), f2bf(q.w)};
                }
                acc = __builtin_amdgcn_mfma_f32_16x16x32_bf16(a1f[ks], bf, acc, 0, 0, 0);
            }
            int o = nt * 16 + ln;
            float sc = scs[64 + o], of = ofs[64 + o];
#pragma unroll
            for (int reg = 0; reg < 4; ++reg) {
                float y = fmaxf(fmaf(acc[reg], sc, of), 0.f);
                featB[(16 * wq + quad * 4 + reg) * 72 + o] = f2bf(y);
            }
        }
    }
    // no barrier: each wave reads back only its own m-tile rows

    // layer 2: 64 -> 128 via MFMA (8 ntiles x 2 ksteps) + fused k-max
    {
        bf16x8 a2f[2];
#pragma unroll
        for (int ks = 0; ks < 2; ++ks)
            a2f[ks] = *(const bf16x8*)&featB[arow * 72 + ks * 32 + quad * 8];

#pragma unroll
        for (int nt = 0; nt < 8; ++nt) {
            f32x4 acc = {0.f, 0.f, 0.f, 0.f};
#pragma unroll
            for (int ks = 0; ks < 2; ++ks) {
                int off = (nt * 16 + ln) * 64 + ks * 32 + quad * 8;
                bf16x8 bf;
                if (usebf) {
                    bf = *(const bf16x8*)&wbf[4096 + off];
                } else {
                    const float* wr = w2 + off;
                    float4 p = *(const float4*)wr;
                    float4 q = *(const float4*)(wr + 4);
                    bf = (bf16x8){f2bf(p.x), f2bf(p.y), f2bf(p.z), f2bf(p.w),
                                  f2bf(q.x), f2bf(q.y), f2bf(q.z), f2bf(q.w)};
                }
                acc = __builtin_amdgcn_mfma_f32_16x16x32_bf16(a2f[ks], bf, acc, 0, 0, 0);
            }
            int o = nt * 16 + ln;
            float sc = scs[128 + o], of = ofs[128 + o];
            float m = -1.f;
#pragma unroll
            for (int reg = 0; reg < 4; ++reg) {
                float y = fmaxf(fmaf(acc[reg], sc, of), 0.f);
                m = fmaxf(m, y);
            }
            m = fmaxf(m, __shfl_xor(m, 16, 64));
            m = fmaxf(m, __shfl_xor(m, 32, 64));
            if (lane < 16) wmaxs[wq * 132 + o] = m;
        }
    }
    __syncthreads();

    // final: max over the 4 waves' m-tiles, store new_points
    if (t < 128) {
        float m = fmaxf(fmaxf(wmaxs[0 * 132 + t], wmaxs[1 * 132 + t]),
                        fmaxf(wmaxs[2 * 132 + t], wmaxs[3 * 132 + t]));
        out[OUT1 + (b * 128 + t) * S_ + s] = m;
    }
}

extern "C" void kernel_launch(void* const* d_in, const int* in_sizes, int n_in,
                              void* d_out, int out_size, void* d_ws, size_t ws_size,
                              hipStream_t stream) {
    const float* xyz  = (const float*)d_in[0];
    const float* pts  = (const float*)d_in[1];
    const int*   seed = (const int*)d_in[2];
    const float* w0 = (const float*)d_in[3];
    const float* b0 = (const float*)d_in[4];
    const float* g0 = (const float*)d_in[5];
    const float* be0 = (const float*)d_in[6];
    const float* m0 = (const float*)d_in[7];
    const float* v0 = (const float*)d_in[8];
    const float* w1 = (const float*)d_in[9];
    const float* b1 = (const float*)d_in[10];
    const float* g1 = (const float*)d_in[11];
    const float* be1 = (const float*)d_in[12];
    const float* m1 = (const float*)d_in[13];
    const float* v1 = (const float*)d_in[14];
    const float* w2 = (const float*)d_in[15];
    const float* b2 = (const float*)d_in[16];
    const float* g2 = (const float*)d_in[17];
    const float* be2 = (const float*)d_in[18];
    const float* m2 = (const float*)d_in[19];
    const float* v2 = (const float*)d_in[20];
    float* out = (float*)d_out;

    short* wbf = nullptr;
    if (ws_size >= 12288 * sizeof(short)) {
        wbf = (short*)d_ws;
        wconv_kernel<<<dim3(48), dim3(256), 0, stream>>>(w1, w2, wbf);
    }

    fps_kernel<<<dim3(B_), dim3(FPS_T), 0, stream>>>(xyz, out);
    down_kernel<<<dim3(B_ * S_), dim3(256), 0, stream>>>(xyz, pts, seed,
        w0, b0, g0, be0, m0, v0,
        w1, b1, g1, be1, m1, v1,
        w2, b2, g2, be2, m2, v2,
        out, wbf);
}